// Round 5
// baseline (252.957 us; speedup 1.0000x reference)
//
#include <hip/hip_runtime.h>

using US   = unsigned short;
using bf8  = __attribute__((ext_vector_type(8))) __bf16;
using us8  = __attribute__((ext_vector_type(8))) US;
using us4  = __attribute__((ext_vector_type(4))) US;
using f4   = __attribute__((ext_vector_type(4))) float;
using f8   = __attribute__((ext_vector_type(8))) float;
using f16v = __attribute__((ext_vector_type(16))) float;

__device__ __forceinline__ US f2bf(float x) {
  union { float f; unsigned u; } v; v.f = x;
  unsigned r = v.u + 0x7fffu + ((v.u >> 16) & 1u);
  return (US)(r >> 16);
}
__device__ __forceinline__ unsigned cvtpk(float a, float b) {
  unsigned r;
  asm("v_cvt_pk_bf16_f32 %0, %1, %2" : "=v"(r) : "v"(a), "v"(b));
  return r;
}

// ---------- fp32 -> bf16 elementwise, 8 elems/lane ----------
__global__ void cvt_k(const float* __restrict__ in, US* __restrict__ out, int n8) {
  int i = blockIdx.x * blockDim.x + threadIdx.x;
  if (i >= n8) return;
  f8 v = ((const f8*)in)[i];
  us8 o;
#pragma unroll
  for (int j = 0; j < 8; ++j) o[j] = f2bf(v[j]);
  ((us8*)out)[i] = o;
}

// ---------- fp32 (R x C) -> bf16 (C x R) transpose ----------
__global__ void trw_k(const float* __restrict__ in, US* __restrict__ out, int R, int C) {
  __shared__ float tile[32][33];
  int bx = blockIdx.x * 32, by = blockIdx.y * 32;
  int tx = threadIdx.x & 31, ty = threadIdx.x >> 5;
  for (int i = ty; i < 32; i += 8)
    tile[i][tx] = in[(size_t)(by + i) * C + bx + tx];
  __syncthreads();
  for (int i = ty; i < 32; i += 8)
    out[(size_t)(bx + i) * R + by + tx] = f2bf(tile[tx][i]);
}

// ---------- V slice of qkv (bf16) -> Vt[b][h][d][t] ----------
__global__ void trv_k(const US* __restrict__ qkv, US* __restrict__ vt) {
  __shared__ US tile[32][33];
  int bh = blockIdx.z;
  int b = bh >> 4;
  int t0 = blockIdx.x * 32, d0 = blockIdx.y * 32;
  int tx = threadIdx.x & 31, ty = threadIdx.x >> 5;
  const US* src = qkv + (size_t)b * 2048 * 3072 + 2048 + (bh & 15) * 64;
  for (int i = ty; i < 32; i += 8)
    tile[i][tx] = src[(size_t)(t0 + i) * 3072 + d0 + tx];
  __syncthreads();
  US* dst = vt + (size_t)bh * 64 * 2048;
  for (int i = ty; i < 32; i += 8)
    dst[(size_t)(d0 + i) * 2048 + t0 + tx] = tile[tx][i];
}

// ---------- C[M,N] = A[M,K](bf16) * Bt[N,K](bf16)^T + bias(f32) ----------
template <typename OT>
__global__ void gemm_bt(const US* __restrict__ A, const US* __restrict__ Bt,
                        const float* __restrict__ bias, OT* __restrict__ out,
                        int M, int N, int K) {
  __shared__ US lA[128 * 64];
  __shared__ US lB[128 * 64];
  const int t = threadIdx.x;
  const int lane = t & 63;
  const int w = t >> 6;
  const int wr = w >> 1, wc = w & 1;
  const int l15 = lane & 15, g = lane >> 4;
  const int m0 = blockIdx.x * 128, n0 = blockIdx.y * 128;

  f4 acc[4][4] = {};

  for (int k0 = 0; k0 < K; k0 += 64) {
    __syncthreads();
#pragma unroll
    for (int i = 0; i < 4; ++i) {
      int e = i * 2048 + t * 8;
      int row = e >> 6, kc = e & 63;
      int byteoff = ((row * 64 + kc) * 2) ^ ((row & 7) << 4);
      us8 va = *(const us8*)(A + (size_t)(m0 + row) * K + k0 + kc);
      *(us8*)((char*)lA + byteoff) = va;
      us8 vb = *(const us8*)(Bt + (size_t)(n0 + row) * K + k0 + kc);
      *(us8*)((char*)lB + byteoff) = vb;
    }
    __syncthreads();
#pragma unroll
    for (int ks = 0; ks < 2; ++ks) {
      bf8 af[4], bfr[4];
#pragma unroll
      for (int mi = 0; mi < 4; ++mi) {
        int row = wr * 64 + mi * 16 + l15;
        int byteoff = row * 128 + (((ks * 32 + g * 8) * 2) ^ ((row & 7) << 4));
        af[mi] = *(const bf8*)((const char*)lA + byteoff);
      }
#pragma unroll
      for (int ni = 0; ni < 4; ++ni) {
        int row = wc * 64 + ni * 16 + l15;
        int byteoff = row * 128 + (((ks * 32 + g * 8) * 2) ^ ((row & 7) << 4));
        bfr[ni] = *(const bf8*)((const char*)lB + byteoff);
      }
#pragma unroll
      for (int mi = 0; mi < 4; ++mi)
#pragma unroll
        for (int ni = 0; ni < 4; ++ni)
          acc[mi][ni] = __builtin_amdgcn_mfma_f32_16x16x32_bf16(af[mi], bfr[ni], acc[mi][ni], 0, 0, 0);
    }
  }
#pragma unroll
  for (int ni = 0; ni < 4; ++ni) {
    int col = n0 + wc * 64 + ni * 16 + l15;
    float bv = bias ? bias[col] : 0.0f;
#pragma unroll
    for (int mi = 0; mi < 4; ++mi) {
      int rowb = m0 + wr * 64 + mi * 16 + g * 4;
#pragma unroll
      for (int r = 0; r < 4; ++r) {
        float val = acc[mi][ni][r] + bv;
        if constexpr (sizeof(OT) == 2)
          out[(size_t)(rowb + r) * N + col] = f2bf(val);
        else
          out[(size_t)(rowb + r) * N + col] = val;
      }
    }
  }
}

// ---------- flash attention, swapped 32x32 MFMA, lane-local softmax, split-KV ----------
// Block = 32 q-rows. Wave w handles keys [w*1024, w*1024+1024); partials merged
// in LDS at block end (exact flash combine). Lane owns q = lane&31.
__global__ __launch_bounds__(128, 4) void attn_k(const US* __restrict__ qkv,
                                                 const US* __restrict__ vt,
                                                 const int* __restrict__ mask,
                                                 US* __restrict__ y) {
  int f = blockIdx.x;                 // 0..2047
  f = ((f & 7) << 8) | (f >> 3);      // XCD bijective remap (2048 = 8*256): 4 heads/XCD
  const int qt = f & 63;              // 64 q-tiles of 32 rows
  const int bh = f >> 6;              // 0..31
  const int b = bh >> 4;
  const int lane = threadIdx.x & 63, w = threadIdx.x >> 6;
  const int l31 = lane & 31, hi = lane >> 5;
  const int qr0 = qt * 32;

  __shared__ float xch[64][34];       // wave-1 partials: 32 O + m + l per lane

  // Q fragments (B-layout: col=q=l31, dh = ks*16 + hi*8 + i), resident
  const US* qrow = qkv + (size_t)(b * 2048 + qr0 + l31) * 3072 + (bh & 15) * 64 + hi * 8;
  bf8 qf[4];
#pragma unroll
  for (int ks = 0; ks < 4; ++ks) qf[ks] = *(const bf8*)(qrow + ks * 16);

  const US* kbase = qkv + (size_t)b * 2048 * 3072 + 1024 + (bh & 15) * 64 + hi * 8;
  const US* vbase = vt + (size_t)bh * 64 * 2048 + (size_t)l31 * 2048 + hi * 8;
  const int* mb = mask + b * 2048;

  f16v o0 = {}, o1 = {};              // O^T: col=q=l31, rows d = r(reg,hi) (+32)
  float m = -1e30f, lrow = 0.0f;
  const float SC = 0.125f * 1.44269504089f;  // scale * log2(e)

  const int kv0 = w * 1024;
  for (int j0 = kv0; j0 < kv0 + 1024; j0 += 64) {
    unsigned long long mbits = __ballot(mb[j0 + lane] != 0);
    // K fragments (A-layout: row=k=l31(+32t), dh = ks*16 + hi*8 + i)
    bf8 ka0[4], ka1[4];
#pragma unroll
    for (int ks = 0; ks < 4; ++ks) {
      ka0[ks] = *(const bf8*)(kbase + (size_t)(j0 + l31) * 3072 + ks * 16);
      ka1[ks] = *(const bf8*)(kbase + (size_t)(j0 + 32 + l31) * 3072 + ks * 16);
    }
    // S^T = K * Q : col=q, row=k
    f16v s0 = {}, s1 = {};
    __builtin_amdgcn_s_setprio(1);
#pragma unroll
    for (int ks = 0; ks < 4; ++ks) {
      s0 = __builtin_amdgcn_mfma_f32_32x32x16_bf16(ka0[ks], qf[ks], s0, 0, 0, 0);
      s1 = __builtin_amdgcn_mfma_f32_32x32x16_bf16(ka1[ks], qf[ks], s1, 0, 0, 0);
    }
    __builtin_amdgcn_s_setprio(0);
    // V fragments issued now; latency hides under softmax
    bf8 vf0[4], vf1[4];
#pragma unroll
    for (int ks = 0; ks < 4; ++ks) {
      vf0[ks] = *(const bf8*)(vbase + j0 + ks * 16);
      vf1[ks] = *(const bf8*)(vbase + 32 * 2048 + j0 + ks * 16);
    }
    // ---- lane-local online softmax over this lane's 32 keys + partner's 32 ----
    float a[16];
#pragma unroll
    for (int i = 0; i < 16; ++i) a[i] = fmaxf(s0[i], s1[i]);
#pragma unroll
    for (int st = 8; st >= 1; st >>= 1)
#pragma unroll
      for (int i = 0; i < 16; ++i)
        if (i < st) a[i] = fmaxf(a[i], a[i + st]);
    float mraw = fmaxf(a[0], __shfl_xor(a[0], 32));
    float pm = mraw * SC;
    if (!__all(pm - m <= 11.5f)) {    // rare rescale (always on first tile)
      float mn = fmaxf(m, pm);
      float fac = exp2f(m - mn);
      m = mn;
      lrow *= fac;
      o0 *= fac;
      o1 *= fac;
    }
#pragma unroll
    for (int i = 0; i < 16; ++i) {
      s0[i] = exp2f(s0[i] * SC - m);
      s1[i] = exp2f(s1[i] * SC - m);
    }
    if (~mbits != 0ULL) {             // partial mask: zero out masked keys
#pragma unroll
      for (int i = 0; i < 16; ++i) {
        int r = (i & 3) + 8 * (i >> 2) + 4 * hi;
        if (!((mbits >> r) & 1)) s0[i] = 0.0f;
        if (!((mbits >> (32 + r)) & 1)) s1[i] = 0.0f;
      }
    }
#pragma unroll
    for (int i = 0; i < 16; ++i) a[i] = s0[i] + s1[i];
#pragma unroll
    for (int st = 8; st >= 1; st >>= 1)
#pragma unroll
      for (int i = 0; i < 16; ++i)
        if (i < st) a[i] += a[i + st];
    lrow += a[0] + __shfl_xor(a[0], 32);
    // ---- P -> bf16 B-fragments (col=q, k = ks*16 + hi*8 + i) via pack+swap ----
    bf8 pf[4];
#pragma unroll
    for (int ks = 0; ks < 4; ++ks) {
      const f16v& st = (ks < 2) ? s0 : s1;
      const int R = (ks & 1) * 8;
      unsigned w0 = cvtpk(st[R + 0], st[R + 1]);
      unsigned w1 = cvtpk(st[R + 2], st[R + 3]);
      unsigned w2 = cvtpk(st[R + 4], st[R + 5]);
      unsigned w3 = cvtpk(st[R + 6], st[R + 7]);
      unsigned sa = hi ? w0 : w2;
      unsigned sb = hi ? w1 : w3;
      unsigned ra = (unsigned)__shfl_xor((int)sa, 32);
      unsigned rb = (unsigned)__shfl_xor((int)sb, 32);
      union { unsigned u[4]; bf8 v; } bld;
      bld.u[0] = hi ? ra : w0;
      bld.u[1] = hi ? rb : w1;
      bld.u[2] = hi ? w2 : ra;
      bld.u[3] = hi ? w3 : rb;
      pf[ks] = bld.v;
    }
    // ---- O^T += Vt * P ----
    __builtin_amdgcn_s_setprio(1);
#pragma unroll
    for (int ks = 0; ks < 4; ++ks) {
      o0 = __builtin_amdgcn_mfma_f32_32x32x16_bf16(vf0[ks], pf[ks], o0, 0, 0, 0);
      o1 = __builtin_amdgcn_mfma_f32_32x32x16_bf16(vf1[ks], pf[ks], o1, 0, 0, 0);
    }
    __builtin_amdgcn_s_setprio(0);
  }
  // ---- split-KV merge: wave 1 publishes partials, wave 0 combines + stores ----
  if (w == 1) {
#pragma unroll
    for (int i = 0; i < 16; ++i) xch[lane][i] = o0[i];
#pragma unroll
    for (int i = 0; i < 16; ++i) xch[lane][16 + i] = o1[i];
    xch[lane][32] = m;
    xch[lane][33] = lrow;
  }
  __syncthreads();
  if (w == 0) {
    float m1 = xch[lane][32], l1 = xch[lane][33];
    float M = fmaxf(m, m1);
    float f0 = exp2f(m - M), f1 = exp2f(m1 - M);
    float inv = 1.0f / (f0 * lrow + f1 * l1);
    float c0 = f0 * inv, c1 = f1 * inv;
    US* yrow = y + (size_t)(b * 2048 + qr0 + l31) * 1024 + (bh & 15) * 64;
#pragma unroll
    for (int qd = 0; qd < 4; ++qd) {
      us4 pk0, pk1;
#pragma unroll
      for (int j = 0; j < 4; ++j) {
        int i = qd * 4 + j;
        pk0[j] = f2bf(o0[i] * c0 + xch[lane][i] * c1);
        pk1[j] = f2bf(o1[i] * c0 + xch[lane][16 + i] * c1);
      }
      *(us4*)(yrow + qd * 8 + hi * 4) = pk0;
      *(us4*)(yrow + 32 + qd * 8 + hi * 4) = pk1;
    }
  }
}

extern "C" void kernel_launch(void* const* d_in, const int* in_sizes, int n_in,
                              void* d_out, int out_size, void* d_ws, size_t ws_size,
                              hipStream_t stream) {
  const float* x     = (const float*)d_in[0];
  const int*   mask  = (const int*)d_in[1];
  const float* Wqkv  = (const float*)d_in[2];
  const float* bqkv  = (const float*)d_in[3];
  const float* Wproj = (const float*)d_in[4];
  const float* bproj = (const float*)d_in[5];
  float* out = (float*)d_out;

  US* xb     = (US*)d_ws;                        // 4096*1024
  US* qkvb   = xb     + (size_t)4096 * 1024;     // 4096*3072
  US* WqkvT  = qkvb   + (size_t)4096 * 3072;     // 3072*1024
  US* WprojT = WqkvT  + (size_t)3072 * 1024;     // 1024*1024
  US* Vt     = WprojT + (size_t)1024 * 1024;     // 32*64*2048
  US* yb     = Vt     + (size_t)32 * 64 * 2048;  // 4096*1024

  cvt_k<<<2048, 256, 0, stream>>>(x, xb, 4096 * 1024 / 8);
  trw_k<<<dim3(96, 32), 256, 0, stream>>>(Wqkv, WqkvT, 1024, 3072);
  trw_k<<<dim3(32, 32), 256, 0, stream>>>(Wproj, WprojT, 1024, 1024);
  gemm_bt<US><<<dim3(32, 24), 256, 0, stream>>>(xb, WqkvT, bqkv, qkvb, 4096, 3072, 1024);
  trv_k<<<dim3(64, 2, 32), 256, 0, stream>>>(qkvb, Vt);
  attn_k<<<2048, 128, 0, stream>>>(qkvb, Vt, mask, yb);
  gemm_bt<float><<<dim3(32, 8), 256, 0, stream>>>(yb, WprojT, bproj, out, 4096, 1024, 1024);
}

// Round 6
// 200.800 us; speedup vs baseline: 1.2597x; 1.2597x over previous
//
#include <hip/hip_runtime.h>

using US   = unsigned short;
using bf8  = __attribute__((ext_vector_type(8))) __bf16;
using us8  = __attribute__((ext_vector_type(8))) US;
using us4  = __attribute__((ext_vector_type(4))) US;
using f4   = __attribute__((ext_vector_type(4))) float;
using f8   = __attribute__((ext_vector_type(8))) float;
using f16v = __attribute__((ext_vector_type(16))) float;

__device__ __forceinline__ US f2bf(float x) {
  union { float f; unsigned u; } v; v.f = x;
  unsigned r = v.u + 0x7fffu + ((v.u >> 16) & 1u);
  return (US)(r >> 16);
}
__device__ __forceinline__ unsigned cvtpk(float a, float b) {
  unsigned r;
  asm("v_cvt_pk_bf16_f32 %0, %1, %2" : "=v"(r) : "v"(a), "v"(b));
  return r;
}

// ---------- fp32 -> bf16 elementwise, 8 elems/lane ----------
__global__ void cvt_k(const float* __restrict__ in, US* __restrict__ out, int n8) {
  int i = blockIdx.x * blockDim.x + threadIdx.x;
  if (i >= n8) return;
  f8 v = ((const f8*)in)[i];
  us8 o;
#pragma unroll
  for (int j = 0; j < 8; ++j) o[j] = f2bf(v[j]);
  ((us8*)out)[i] = o;
}

// ---------- fp32 (R x C) -> bf16 (C x R) transpose ----------
__global__ void trw_k(const float* __restrict__ in, US* __restrict__ out, int R, int C) {
  __shared__ float tile[32][33];
  int bx = blockIdx.x * 32, by = blockIdx.y * 32;
  int tx = threadIdx.x & 31, ty = threadIdx.x >> 5;
  for (int i = ty; i < 32; i += 8)
    tile[i][tx] = in[(size_t)(by + i) * C + bx + tx];
  __syncthreads();
  for (int i = ty; i < 32; i += 8)
    out[(size_t)(bx + i) * R + by + tx] = f2bf(tile[tx][i]);
}

// ---------- V slice of qkv (bf16) -> Vt[b][h][d][t] ----------
__global__ void trv_k(const US* __restrict__ qkv, US* __restrict__ vt) {
  __shared__ US tile[32][33];
  int bh = blockIdx.z;
  int b = bh >> 4;
  int t0 = blockIdx.x * 32, d0 = blockIdx.y * 32;
  int tx = threadIdx.x & 31, ty = threadIdx.x >> 5;
  const US* src = qkv + (size_t)b * 2048 * 3072 + 2048 + (bh & 15) * 64;
  for (int i = ty; i < 32; i += 8)
    tile[i][tx] = src[(size_t)(t0 + i) * 3072 + d0 + tx];
  __syncthreads();
  US* dst = vt + (size_t)bh * 64 * 2048;
  for (int i = ty; i < 32; i += 8)
    dst[(size_t)(d0 + i) * 2048 + t0 + tx] = tile[tx][i];
}

// ---------- C[M,N] = A[M,K](bf16) * Bt[N,K](bf16)^T + bias(f32) ----------
template <typename OT>
__global__ void gemm_bt(const US* __restrict__ A, const US* __restrict__ Bt,
                        const float* __restrict__ bias, OT* __restrict__ out,
                        int M, int N, int K) {
  __shared__ US lA[128 * 64];
  __shared__ US lB[128 * 64];
  const int t = threadIdx.x;
  const int lane = t & 63;
  const int w = t >> 6;
  const int wr = w >> 1, wc = w & 1;
  const int l15 = lane & 15, g = lane >> 4;
  const int m0 = blockIdx.x * 128, n0 = blockIdx.y * 128;

  f4 acc[4][4] = {};

  for (int k0 = 0; k0 < K; k0 += 64) {
    __syncthreads();
#pragma unroll
    for (int i = 0; i < 4; ++i) {
      int e = i * 2048 + t * 8;
      int row = e >> 6, kc = e & 63;
      int byteoff = ((row * 64 + kc) * 2) ^ ((row & 7) << 4);
      us8 va = *(const us8*)(A + (size_t)(m0 + row) * K + k0 + kc);
      *(us8*)((char*)lA + byteoff) = va;
      us8 vb = *(const us8*)(Bt + (size_t)(n0 + row) * K + k0 + kc);
      *(us8*)((char*)lB + byteoff) = vb;
    }
    __syncthreads();
#pragma unroll
    for (int ks = 0; ks < 2; ++ks) {
      bf8 af[4], bfr[4];
#pragma unroll
      for (int mi = 0; mi < 4; ++mi) {
        int row = wr * 64 + mi * 16 + l15;
        int byteoff = row * 128 + (((ks * 32 + g * 8) * 2) ^ ((row & 7) << 4));
        af[mi] = *(const bf8*)((const char*)lA + byteoff);
      }
#pragma unroll
      for (int ni = 0; ni < 4; ++ni) {
        int row = wc * 64 + ni * 16 + l15;
        int byteoff = row * 128 + (((ks * 32 + g * 8) * 2) ^ ((row & 7) << 4));
        bfr[ni] = *(const bf8*)((const char*)lB + byteoff);
      }
#pragma unroll
      for (int mi = 0; mi < 4; ++mi)
#pragma unroll
        for (int ni = 0; ni < 4; ++ni)
          acc[mi][ni] = __builtin_amdgcn_mfma_f32_16x16x32_bf16(af[mi], bfr[ni], acc[mi][ni], 0, 0, 0);
    }
  }
#pragma unroll
  for (int ni = 0; ni < 4; ++ni) {
    int col = n0 + wc * 64 + ni * 16 + l15;
    float bv = bias ? bias[col] : 0.0f;
#pragma unroll
    for (int mi = 0; mi < 4; ++mi) {
      int rowb = m0 + wr * 64 + mi * 16 + g * 4;
#pragma unroll
      for (int r = 0; r < 4; ++r) {
        float val = acc[mi][ni][r] + bv;
        if constexpr (sizeof(OT) == 2)
          out[(size_t)(rowb + r) * N + col] = f2bf(val);
        else
          out[(size_t)(rowb + r) * N + col] = val;
      }
    }
  }
}

// ---------- flash attention, swapped 32x32 MFMA, lane-local softmax, split-KV ----------
// Block = 32 q-rows. Wave w handles keys [w*1024, w*1024+1024); partials merged
// in LDS at block end (exact flash combine). Lane owns q = lane&31.
// NOTE: launch_bounds min-waves MUST stay 2 — asking for 4 caps VGPR at 64 and
// spills the f16v accumulators to scratch (round-5 regression: WRITE_SIZE 192MB).
__global__ __launch_bounds__(128, 2) void attn_k(const US* __restrict__ qkv,
                                                 const US* __restrict__ vt,
                                                 const int* __restrict__ mask,
                                                 US* __restrict__ y) {
  int f = blockIdx.x;                 // 0..2047
  f = ((f & 7) << 8) | (f >> 3);      // XCD bijective remap (2048 = 8*256): 4 heads/XCD
  const int qt = f & 63;              // 64 q-tiles of 32 rows
  const int bh = f >> 6;              // 0..31
  const int b = bh >> 4;
  const int lane = threadIdx.x & 63, w = threadIdx.x >> 6;
  const int l31 = lane & 31, hi = lane >> 5;
  const int qr0 = qt * 32;

  __shared__ float xch[64][34];       // wave-1 partials: 32 O + m + l per lane

  // Q fragments (B-layout: col=q=l31, dh = ks*16 + hi*8 + i), resident
  const US* qrow = qkv + (size_t)(b * 2048 + qr0 + l31) * 3072 + (bh & 15) * 64 + hi * 8;
  bf8 qf[4];
#pragma unroll
  for (int ks = 0; ks < 4; ++ks) qf[ks] = *(const bf8*)(qrow + ks * 16);

  const US* kbase = qkv + (size_t)b * 2048 * 3072 + 1024 + (bh & 15) * 64 + hi * 8;
  const US* vbase = vt + (size_t)bh * 64 * 2048 + (size_t)l31 * 2048 + hi * 8;
  const int* mb = mask + b * 2048;

  f16v o0 = {}, o1 = {};              // O^T: col=q=l31, rows d = r(reg,hi) (+32)
  float m = -1e30f, lrow = 0.0f;
  const float SC = 0.125f * 1.44269504089f;  // scale * log2(e)

  const int kv0 = w * 1024;
  for (int j0 = kv0; j0 < kv0 + 1024; j0 += 64) {
    unsigned long long mbits = __ballot(mb[j0 + lane] != 0);
    // K fragments (A-layout: row=k=l31(+32t), dh = ks*16 + hi*8 + i)
    bf8 ka0[4], ka1[4];
#pragma unroll
    for (int ks = 0; ks < 4; ++ks) {
      ka0[ks] = *(const bf8*)(kbase + (size_t)(j0 + l31) * 3072 + ks * 16);
      ka1[ks] = *(const bf8*)(kbase + (size_t)(j0 + 32 + l31) * 3072 + ks * 16);
    }
    // S^T = K * Q : col=q, row=k
    f16v s0 = {}, s1 = {};
    __builtin_amdgcn_s_setprio(1);
#pragma unroll
    for (int ks = 0; ks < 4; ++ks) {
      s0 = __builtin_amdgcn_mfma_f32_32x32x16_bf16(ka0[ks], qf[ks], s0, 0, 0, 0);
      s1 = __builtin_amdgcn_mfma_f32_32x32x16_bf16(ka1[ks], qf[ks], s1, 0, 0, 0);
    }
    __builtin_amdgcn_s_setprio(0);
    // V fragments issued now; latency hides under softmax
    bf8 vf0[4], vf1[4];
#pragma unroll
    for (int ks = 0; ks < 4; ++ks) {
      vf0[ks] = *(const bf8*)(vbase + j0 + ks * 16);
      vf1[ks] = *(const bf8*)(vbase + 32 * 2048 + j0 + ks * 16);
    }
    // ---- lane-local online softmax over this lane's 32 keys + partner's 32 ----
    float a[16];
#pragma unroll
    for (int i = 0; i < 16; ++i) a[i] = fmaxf(s0[i], s1[i]);
#pragma unroll
    for (int st = 8; st >= 1; st >>= 1)
#pragma unroll
      for (int i = 0; i < 16; ++i)
        if (i < st) a[i] = fmaxf(a[i], a[i + st]);
    float mraw = fmaxf(a[0], __shfl_xor(a[0], 32));
    float pm = mraw * SC;
    if (!__all(pm - m <= 11.5f)) {    // rare rescale (always on first tile)
      float mn = fmaxf(m, pm);
      float fac = exp2f(m - mn);
      m = mn;
      lrow *= fac;
      o0 *= fac;
      o1 *= fac;
    }
#pragma unroll
    for (int i = 0; i < 16; ++i) {
      s0[i] = exp2f(s0[i] * SC - m);
      s1[i] = exp2f(s1[i] * SC - m);
    }
    if (~mbits != 0ULL) {             // partial mask: zero out masked keys
#pragma unroll
      for (int i = 0; i < 16; ++i) {
        int r = (i & 3) + 8 * (i >> 2) + 4 * hi;
        if (!((mbits >> r) & 1)) s0[i] = 0.0f;
        if (!((mbits >> (32 + r)) & 1)) s1[i] = 0.0f;
      }
    }
#pragma unroll
    for (int i = 0; i < 16; ++i) a[i] = s0[i] + s1[i];
#pragma unroll
    for (int st = 8; st >= 1; st >>= 1)
#pragma unroll
      for (int i = 0; i < 16; ++i)
        if (i < st) a[i] += a[i + st];
    lrow += a[0] + __shfl_xor(a[0], 32);
    // ---- P -> bf16 B-fragments (col=q, k = ks*16 + hi*8 + i) via pack+swap ----
    bf8 pf[4];
#pragma unroll
    for (int ks = 0; ks < 4; ++ks) {
      const f16v& st = (ks < 2) ? s0 : s1;
      const int R = (ks & 1) * 8;
      unsigned w0 = cvtpk(st[R + 0], st[R + 1]);
      unsigned w1 = cvtpk(st[R + 2], st[R + 3]);
      unsigned w2 = cvtpk(st[R + 4], st[R + 5]);
      unsigned w3 = cvtpk(st[R + 6], st[R + 7]);
      unsigned sa = hi ? w0 : w2;
      unsigned sb = hi ? w1 : w3;
      unsigned ra = (unsigned)__shfl_xor((int)sa, 32);
      unsigned rb = (unsigned)__shfl_xor((int)sb, 32);
      union { unsigned u[4]; bf8 v; } bld;
      bld.u[0] = hi ? ra : w0;
      bld.u[1] = hi ? rb : w1;
      bld.u[2] = hi ? w2 : ra;
      bld.u[3] = hi ? w3 : rb;
      pf[ks] = bld.v;
    }
    // ---- O^T += Vt * P ----
    __builtin_amdgcn_s_setprio(1);
#pragma unroll
    for (int ks = 0; ks < 4; ++ks) {
      o0 = __builtin_amdgcn_mfma_f32_32x32x16_bf16(vf0[ks], pf[ks], o0, 0, 0, 0);
      o1 = __builtin_amdgcn_mfma_f32_32x32x16_bf16(vf1[ks], pf[ks], o1, 0, 0, 0);
    }
    __builtin_amdgcn_s_setprio(0);
  }
  // ---- split-KV merge: wave 1 publishes partials, wave 0 combines + stores ----
  if (w == 1) {
#pragma unroll
    for (int i = 0; i < 16; ++i) xch[lane][i] = o0[i];
#pragma unroll
    for (int i = 0; i < 16; ++i) xch[lane][16 + i] = o1[i];
    xch[lane][32] = m;
    xch[lane][33] = lrow;
  }
  __syncthreads();
  if (w == 0) {
    float m1 = xch[lane][32], l1 = xch[lane][33];
    float M = fmaxf(m, m1);
    float f0 = exp2f(m - M), f1 = exp2f(m1 - M);
    float inv = 1.0f / (f0 * lrow + f1 * l1);
    float c0 = f0 * inv, c1 = f1 * inv;
    US* yrow = y + (size_t)(b * 2048 + qr0 + l31) * 1024 + (bh & 15) * 64;
#pragma unroll
    for (int qd = 0; qd < 4; ++qd) {
      us4 pk0, pk1;
#pragma unroll
      for (int j = 0; j < 4; ++j) {
        int i = qd * 4 + j;
        pk0[j] = f2bf(o0[i] * c0 + xch[lane][i] * c1);
        pk1[j] = f2bf(o1[i] * c0 + xch[lane][16 + i] * c1);
      }
      *(us4*)(yrow + qd * 8 + hi * 4) = pk0;
      *(us4*)(yrow + 32 + qd * 8 + hi * 4) = pk1;
    }
  }
}

extern "C" void kernel_launch(void* const* d_in, const int* in_sizes, int n_in,
                              void* d_out, int out_size, void* d_ws, size_t ws_size,
                              hipStream_t stream) {
  const float* x     = (const float*)d_in[0];
  const int*   mask  = (const int*)d_in[1];
  const float* Wqkv  = (const float*)d_in[2];
  const float* bqkv  = (const float*)d_in[3];
  const float* Wproj = (const float*)d_in[4];
  const float* bproj = (const float*)d_in[5];
  float* out = (float*)d_out;

  US* xb     = (US*)d_ws;                        // 4096*1024
  US* qkvb   = xb     + (size_t)4096 * 1024;     // 4096*3072
  US* WqkvT  = qkvb   + (size_t)4096 * 3072;     // 3072*1024
  US* WprojT = WqkvT  + (size_t)3072 * 1024;     // 1024*1024
  US* Vt     = WprojT + (size_t)1024 * 1024;     // 32*64*2048
  US* yb     = Vt     + (size_t)32 * 64 * 2048;  // 4096*1024

  cvt_k<<<2048, 256, 0, stream>>>(x, xb, 4096 * 1024 / 8);
  trw_k<<<dim3(96, 32), 256, 0, stream>>>(Wqkv, WqkvT, 1024, 3072);
  trw_k<<<dim3(32, 32), 256, 0, stream>>>(Wproj, WprojT, 1024, 1024);
  gemm_bt<US><<<dim3(32, 24), 256, 0, stream>>>(xb, WqkvT, bqkv, qkvb, 4096, 3072, 1024);
  trv_k<<<dim3(64, 2, 32), 256, 0, stream>>>(qkvb, Vt);
  attn_k<<<2048, 128, 0, stream>>>(qkvb, Vt, mask, yb);
  gemm_bt<float><<<dim3(32, 8), 256, 0, stream>>>(yb, WprojT, bproj, out, 4096, 1024, 1024);
}

// Round 7
// 151.443 us; speedup vs baseline: 1.6703x; 1.3259x over previous
//
#include <hip/hip_runtime.h>

using US   = unsigned short;
using bf8  = __attribute__((ext_vector_type(8))) __bf16;
using us8  = __attribute__((ext_vector_type(8))) US;
using us4  = __attribute__((ext_vector_type(4))) US;
using f4   = __attribute__((ext_vector_type(4))) float;
using f8   = __attribute__((ext_vector_type(8))) float;
using f16v = __attribute__((ext_vector_type(16))) float;

__device__ __forceinline__ US f2bf(float x) {
  union { float f; unsigned u; } v; v.f = x;
  unsigned r = v.u + 0x7fffu + ((v.u >> 16) & 1u);
  return (US)(r >> 16);
}
__device__ __forceinline__ unsigned cvtpk(float a, float b) {
  unsigned r;
  asm("v_cvt_pk_bf16_f32 %0, %1, %2" : "=v"(r) : "v"(a), "v"(b));
  return r;
}
// async global->LDS, 16B/lane, linear LDS dest (wave-uniform base + lane*16)
__device__ __forceinline__ void gl16(const US* g, US* l) {
  __builtin_amdgcn_global_load_lds((const __attribute__((address_space(1))) void*)g,
                                   (__attribute__((address_space(3))) void*)l, 16, 0, 0);
}

// ---------- fp32 -> bf16 elementwise, 8 elems/lane ----------
__global__ void cvt_k(const float* __restrict__ in, US* __restrict__ out, int n8) {
  int i = blockIdx.x * blockDim.x + threadIdx.x;
  if (i >= n8) return;
  f8 v = ((const f8*)in)[i];
  us8 o;
#pragma unroll
  for (int j = 0; j < 8; ++j) o[j] = f2bf(v[j]);
  ((us8*)out)[i] = o;
}

// ---------- fp32 (R x C) -> bf16 (C x R) transpose ----------
__global__ void trw_k(const float* __restrict__ in, US* __restrict__ out, int R, int C) {
  __shared__ float tile[32][33];
  int bx = blockIdx.x * 32, by = blockIdx.y * 32;
  int tx = threadIdx.x & 31, ty = threadIdx.x >> 5;
  for (int i = ty; i < 32; i += 8)
    tile[i][tx] = in[(size_t)(by + i) * C + bx + tx];
  __syncthreads();
  for (int i = ty; i < 32; i += 8)
    out[(size_t)(bx + i) * R + by + tx] = f2bf(tile[tx][i]);
}

// ---------- V slice of qkv (bf16) -> Vt[b][h][d][t] ----------
__global__ void trv_k(const US* __restrict__ qkv, US* __restrict__ vt) {
  __shared__ US tile[32][33];
  int bh = blockIdx.z;
  int b = bh >> 4;
  int t0 = blockIdx.x * 32, d0 = blockIdx.y * 32;
  int tx = threadIdx.x & 31, ty = threadIdx.x >> 5;
  const US* src = qkv + (size_t)b * 2048 * 3072 + 2048 + (bh & 15) * 64;
  for (int i = ty; i < 32; i += 8)
    tile[i][tx] = src[(size_t)(t0 + i) * 3072 + d0 + tx];
  __syncthreads();
  US* dst = vt + (size_t)bh * 64 * 2048;
  for (int i = ty; i < 32; i += 8)
    dst[(size_t)(d0 + i) * 2048 + t0 + tx] = tile[tx][i];
}

// ---------- C[M,N] = A[M,K](bf16) * Bt[N,K](bf16)^T + bias(f32) ----------
template <typename OT>
__global__ void gemm_bt(const US* __restrict__ A, const US* __restrict__ Bt,
                        const float* __restrict__ bias, OT* __restrict__ out,
                        int M, int N, int K) {
  __shared__ US lA[128 * 64];
  __shared__ US lB[128 * 64];
  const int t = threadIdx.x;
  const int lane = t & 63;
  const int w = t >> 6;
  const int wr = w >> 1, wc = w & 1;
  const int l15 = lane & 15, g = lane >> 4;
  const int m0 = blockIdx.x * 128, n0 = blockIdx.y * 128;

  f4 acc[4][4] = {};

  for (int k0 = 0; k0 < K; k0 += 64) {
    __syncthreads();
#pragma unroll
    for (int i = 0; i < 4; ++i) {
      int e = i * 2048 + t * 8;
      int row = e >> 6, kc = e & 63;
      int byteoff = ((row * 64 + kc) * 2) ^ ((row & 7) << 4);
      us8 va = *(const us8*)(A + (size_t)(m0 + row) * K + k0 + kc);
      *(us8*)((char*)lA + byteoff) = va;
      us8 vb = *(const us8*)(Bt + (size_t)(n0 + row) * K + k0 + kc);
      *(us8*)((char*)lB + byteoff) = vb;
    }
    __syncthreads();
#pragma unroll
    for (int ks = 0; ks < 2; ++ks) {
      bf8 af[4], bfr[4];
#pragma unroll
      for (int mi = 0; mi < 4; ++mi) {
        int row = wr * 64 + mi * 16 + l15;
        int byteoff = row * 128 + (((ks * 32 + g * 8) * 2) ^ ((row & 7) << 4));
        af[mi] = *(const bf8*)((const char*)lA + byteoff);
      }
#pragma unroll
      for (int ni = 0; ni < 4; ++ni) {
        int row = wc * 64 + ni * 16 + l15;
        int byteoff = row * 128 + (((ks * 32 + g * 8) * 2) ^ ((row & 7) << 4));
        bfr[ni] = *(const bf8*)((const char*)lB + byteoff);
      }
#pragma unroll
      for (int mi = 0; mi < 4; ++mi)
#pragma unroll
        for (int ni = 0; ni < 4; ++ni)
          acc[mi][ni] = __builtin_amdgcn_mfma_f32_16x16x32_bf16(af[mi], bfr[ni], acc[mi][ni], 0, 0, 0);
    }
  }
#pragma unroll
  for (int ni = 0; ni < 4; ++ni) {
    int col = n0 + wc * 64 + ni * 16 + l15;
    float bv = bias ? bias[col] : 0.0f;
#pragma unroll
    for (int mi = 0; mi < 4; ++mi) {
      int rowb = m0 + wr * 64 + mi * 16 + g * 4;
#pragma unroll
      for (int r = 0; r < 4; ++r) {
        float val = acc[mi][ni][r] + bv;
        if constexpr (sizeof(OT) == 2)
          out[(size_t)(rowb + r) * N + col] = f2bf(val);
        else
          out[(size_t)(rowb + r) * N + col] = val;
      }
    }
  }
}

// swizzled LDS fragment read: row r, 16B unit u = 2*ks+hi, byte = r*128 + ((u^(r&7))<<4)
__device__ __forceinline__ const bf8* fragp(const US* base, int r, int ks, int hi) {
  int byte = r * 128 + ((((ks << 1) | hi) ^ (r & 7)) << 4);
  return (const bf8*)((const char*)base + byte);
}

// ---------- flash attention: 4 waves x 32 q-rows, K/V LDS-staged (dbuf) ----------
// Swapped 32x32 MFMA, lane-local softmax (lane owns q = lane&31). K/V tiles are
// staged with global_load_lds (linear LDS dest + pre-swizzled global source,
// XOR-swizzled ds_read) so no fragment registers are held across the tile.
__global__ __launch_bounds__(256, 2) void attn_k(const US* __restrict__ qkv,
                                                 const US* __restrict__ vt,
                                                 const int* __restrict__ mask,
                                                 US* __restrict__ y) {
  int f0 = blockIdx.x;                  // 0..511
  int f = ((f0 & 7) << 6) | (f0 >> 3);  // XCD bijective remap (512 = 8*64): 4 heads/XCD
  const int qt = f & 15;                // 16 q-tiles of 128 rows
  const int bh = f >> 4;                // 0..31
  const int b = bh >> 4;
  const int h = bh & 15;
  const int lane = threadIdx.x & 63, w = threadIdx.x >> 6;
  const int l31 = lane & 31, hi = lane >> 5;

  __shared__ US lK[2][64 * 64];
  __shared__ US lV[2][64 * 64];

  // Q fragments (B operand: col=q=l31, k-dim dh = ks*16 + hi*8 + i), resident
  const int qr0 = qt * 128 + w * 32;
  const US* qrow = qkv + (size_t)(b * 2048 + qr0 + l31) * 3072 + h * 64 + hi * 8;
  bf8 qf[4];
#pragma unroll
  for (int ks = 0; ks < 4; ++ks) qf[ks] = *(const bf8*)(qrow + ks * 16);

  // staging geometry: wave w stages rows [w*16, w*16+16) of both tiles.
  // lane i covers (row_base + i/8, 16B-unit (i&7)); global col pre-swizzled by ^(i/8)
  const int r8 = lane >> 3;
  const int c16 = (lane & 7) ^ r8;
  const US* kg = qkv + (size_t)b * 2048 * 3072 + 1024 + h * 64 + c16 * 8;
  const US* vg = vt + (size_t)bh * 64 * 2048 + c16 * 8;
  const int R0 = w * 16;

  const int* mb = mask + b * 2048;

  f16v o0 = {}, o1 = {};                // O^T: col=q=l31, rows d (+32 for o1)
  float m = -1e30f, lrow = 0.0f;
  const float SC = 0.125f * 1.44269504089f;  // scale * log2(e)

#define STAGE(buf, j0s)                                                        \
  {                                                                            \
    gl16(kg + (size_t)((j0s) + R0 + r8) * 3072, &lK[buf][R0 * 64]);            \
    gl16(kg + (size_t)((j0s) + R0 + 8 + r8) * 3072, &lK[buf][(R0 + 8) * 64]);  \
    gl16(vg + (size_t)(R0 + r8) * 2048 + (j0s), &lV[buf][R0 * 64]);            \
    gl16(vg + (size_t)(R0 + 8 + r8) * 2048 + (j0s), &lV[buf][(R0 + 8) * 64]);  \
  }

  STAGE(0, 0);
  __syncthreads();

  for (int tt = 0; tt < 32; ++tt) {
    const int cur = tt & 1;
    const int j0 = tt * 64;
    int mword = mb[j0 + lane];
    if (tt < 31) STAGE(cur ^ 1, j0 + 64);   // async prefetch next tile
    unsigned long long mbits = __ballot(mword != 0);
    const US* lKc = lK[cur];
    const US* lVc = lV[cur];

    // ---- S^T = K * Q : col=q, row=k ----
    f16v s0 = {}, s1 = {};
    __builtin_amdgcn_s_setprio(1);
#pragma unroll
    for (int ks = 0; ks < 4; ++ks) {
      bf8 ka0 = *fragp(lKc, l31, ks, hi);
      bf8 ka1 = *fragp(lKc, 32 + l31, ks, hi);
      s0 = __builtin_amdgcn_mfma_f32_32x32x16_bf16(ka0, qf[ks], s0, 0, 0, 0);
      s1 = __builtin_amdgcn_mfma_f32_32x32x16_bf16(ka1, qf[ks], s1, 0, 0, 0);
    }
    __builtin_amdgcn_s_setprio(0);

    // ---- lane-local online softmax over this lane's 32 keys + partner's 32 ----
    float a[16];
#pragma unroll
    for (int i = 0; i < 16; ++i) a[i] = fmaxf(s0[i], s1[i]);
#pragma unroll
    for (int st = 8; st >= 1; st >>= 1)
#pragma unroll
      for (int i = 0; i < 16; ++i)
        if (i < st) a[i] = fmaxf(a[i], a[i + st]);
    float mraw = fmaxf(a[0], __shfl_xor(a[0], 32));
    float pm = mraw * SC;
    if (!__all(pm - m <= 11.5f)) {      // rare rescale (always on first tile)
      float mn = fmaxf(m, pm);
      float fac = exp2f(m - mn);
      m = mn;
      lrow *= fac;
      o0 *= fac;
      o1 *= fac;
    }
#pragma unroll
    for (int i = 0; i < 16; ++i) {
      s0[i] = exp2f(s0[i] * SC - m);
      s1[i] = exp2f(s1[i] * SC - m);
    }
    if (~mbits != 0ULL) {               // partial mask: zero out masked keys
#pragma unroll
      for (int i = 0; i < 16; ++i) {
        int r = (i & 3) + 8 * (i >> 2) + 4 * hi;
        if (!((mbits >> r) & 1)) s0[i] = 0.0f;
        if (!((mbits >> (32 + r)) & 1)) s1[i] = 0.0f;
      }
    }
#pragma unroll
    for (int i = 0; i < 16; ++i) a[i] = s0[i] + s1[i];
#pragma unroll
    for (int st = 8; st >= 1; st >>= 1)
#pragma unroll
      for (int i = 0; i < 16; ++i)
        if (i < st) a[i] += a[i + st];
    lrow += a[0] + __shfl_xor(a[0], 32);

    // ---- P -> bf16 B-fragments (col=q, k = ks*16 + hi*8 + i) via pack+swap ----
    bf8 pf[4];
#pragma unroll
    for (int ks = 0; ks < 4; ++ks) {
      const f16v& st = (ks < 2) ? s0 : s1;
      const int R = (ks & 1) * 8;
      unsigned w0 = cvtpk(st[R + 0], st[R + 1]);
      unsigned w1 = cvtpk(st[R + 2], st[R + 3]);
      unsigned w2 = cvtpk(st[R + 4], st[R + 5]);
      unsigned w3 = cvtpk(st[R + 6], st[R + 7]);
      unsigned sa = hi ? w0 : w2;
      unsigned sb = hi ? w1 : w3;
      unsigned ra = (unsigned)__shfl_xor((int)sa, 32);
      unsigned rb = (unsigned)__shfl_xor((int)sb, 32);
      union { unsigned u[4]; bf8 v; } bld;
      bld.u[0] = hi ? ra : w0;
      bld.u[1] = hi ? rb : w1;
      bld.u[2] = hi ? w2 : ra;
      bld.u[3] = hi ? w3 : rb;
      pf[ks] = bld.v;
    }

    // ---- O^T += Vt * P ----
    __builtin_amdgcn_s_setprio(1);
#pragma unroll
    for (int ks = 0; ks < 4; ++ks) {
      bf8 vf0 = *fragp(lVc, l31, ks, hi);
      bf8 vf1 = *fragp(lVc, 32 + l31, ks, hi);
      o0 = __builtin_amdgcn_mfma_f32_32x32x16_bf16(vf0, pf[ks], o0, 0, 0, 0);
      o1 = __builtin_amdgcn_mfma_f32_32x32x16_bf16(vf1, pf[ks], o1, 0, 0, 0);
    }
    __builtin_amdgcn_s_setprio(0);

    __syncthreads();                    // drains staging (vmcnt 0) + read-done sync
  }
#undef STAGE

  // ---- epilogue: lane-local normalize, 8B packed stores ----
  float inv = 1.0f / lrow;
  US* yrow = y + (size_t)(b * 2048 + qr0 + l31) * 1024 + h * 64;
#pragma unroll
  for (int qd = 0; qd < 4; ++qd) {
    us4 pk0, pk1;
#pragma unroll
    for (int j = 0; j < 4; ++j) {
      pk0[j] = f2bf(o0[qd * 4 + j] * inv);
      pk1[j] = f2bf(o1[qd * 4 + j] * inv);
    }
    *(us4*)(yrow + qd * 8 + hi * 4) = pk0;
    *(us4*)(yrow + 32 + qd * 8 + hi * 4) = pk1;
  }
}

extern "C" void kernel_launch(void* const* d_in, const int* in_sizes, int n_in,
                              void* d_out, int out_size, void* d_ws, size_t ws_size,
                              hipStream_t stream) {
  const float* x     = (const float*)d_in[0];
  const int*   mask  = (const int*)d_in[1];
  const float* Wqkv  = (const float*)d_in[2];
  const float* bqkv  = (const float*)d_in[3];
  const float* Wproj = (const float*)d_in[4];
  const float* bproj = (const float*)d_in[5];
  float* out = (float*)d_out;

  US* xb     = (US*)d_ws;                        // 4096*1024
  US* qkvb   = xb     + (size_t)4096 * 1024;     // 4096*3072
  US* WqkvT  = qkvb   + (size_t)4096 * 3072;     // 3072*1024
  US* WprojT = WqkvT  + (size_t)3072 * 1024;     // 1024*1024
  US* Vt     = WprojT + (size_t)1024 * 1024;     // 32*64*2048
  US* yb     = Vt     + (size_t)32 * 64 * 2048;  // 4096*1024

  cvt_k<<<2048, 256, 0, stream>>>(x, xb, 4096 * 1024 / 8);
  trw_k<<<dim3(96, 32), 256, 0, stream>>>(Wqkv, WqkvT, 1024, 3072);
  trw_k<<<dim3(32, 32), 256, 0, stream>>>(Wproj, WprojT, 1024, 1024);
  gemm_bt<US><<<dim3(32, 24), 256, 0, stream>>>(xb, WqkvT, bqkv, qkvb, 4096, 3072, 1024);
  trv_k<<<dim3(64, 2, 32), 256, 0, stream>>>(qkvb, Vt);
  attn_k<<<512, 256, 0, stream>>>(qkvb, Vt, mask, yb);
  gemm_bt<float><<<dim3(32, 8), 256, 0, stream>>>(yb, WprojT, bproj, out, 4096, 1024, 1024);
}